// Round 14
// baseline (123.633 us; speedup 1.0000x reference)
//
#include <hip/hip_runtime.h>

#define N_NODES 65536
#define N_EDGES 1048576
#define DIM 64
#define M_POOL (N_NODES / DIM)  // 1024
#define NCOARSE 256             // coarse buckets (col>>8), 256 nodes each
#define SEGCAP 5120             // fixed region per coarse bucket (mean 4096 + 16 sigma)
#define P3CHUNK 2048            // edges per p3 block
#define P3BLOCKS (N_EDGES / P3CHUNK)   // 512
#define GEMM_BLOCKS 1024               // 65536 rows / 64 per block
#define FUSED_BLOCKS (GEMM_BLOCKS + P3BLOCKS)  // 1536, 2:1 interleave

typedef unsigned int u32;
typedef unsigned short u16;

__device__ __forceinline__ float bf2f(u32 hi16) {
    return __uint_as_float(hi16 << 16);
}
__device__ __forceinline__ u32 f2bf(float f) {  // RNE
    u32 u = __float_as_uint(f);
    return (u + 0x7fffu + ((u >> 16) & 1u)) >> 16;
}

// inclusive scan of arr[256] by threads t<256 (4 full waves), 2 syncs.
// wsum must hold >=4 ints. All threads of the block must reach the syncs.
__device__ __forceinline__ void scan256_wave(int* arr, int* wsum, int t) {
    int s = 0;
    if (t < 256) {
        s = arr[t];
        const int lane = t & 63;
#pragma unroll
        for (int o = 1; o < 64; o <<= 1) {
            const int u = __shfl_up(s, o, 64);
            if (lane >= o) s += u;
        }
        if (lane == 63) wsum[t >> 6] = s;
    }
    __syncthreads();
    if (t < 256) {
        const int w = t >> 6;
        int add = 0;
#pragma unroll
        for (int k = 0; k < 4; ++k)
            if (k < w) add += wsum[k];
        arr[t] = s + add;
    }
    __syncthreads();
}

// ---------------- zero the 256 coarse cursors ----------------

__global__ __launch_bounds__(256) void zero_cursor(int* __restrict__ cursor) {
    cursor[threadIdx.x] = 0;
}

// ---------------- fused: layer-1 GEMM || coarse multisplit scatter ----------
// 1536 blocks x 1024 thr. b%3==2 -> p3 chunk b/3 (2048 edges); else gemm tile
// (b - b/3)*64 rows. Phases share an LDS union buffer (32.5 KB).

__global__ __launch_bounds__(1024) void fused_gemm_p3(const float* __restrict__ x,
                                                      const float* __restrict__ W,
                                                      u16* __restrict__ hb,
                                                      const int* __restrict__ col,
                                                      const int* __restrict__ row,
                                                      const float* __restrict__ ew,
                                                      int* __restrict__ cursor,
                                                      int2* __restrict__ csr_tmp) {
    __shared__ __align__(16) char sm[33280];
    const int t = threadIdx.x;
    const int b = blockIdx.x;

    if ((b % 3) == 2) {
        // ---- p3 block: coarse multisplit of chunk b/3 ----
        int2* stg      = (int2*)sm;              // 16384 B
        int*  gpA      = (int*)(sm + 16384);     //  8192 B
        int*  h2       = (int*)(sm + 24576);     //  1024 B
        int*  off      = (int*)(sm + 25600);     //  1024 B
        int*  base_blk = (int*)(sm + 26624);     //  1024 B
        int*  wsum     = (int*)(sm + 27648);     //    16 B
        const int e0 = (b / 3) * P3CHUNK + t * 2;

        if (t < NCOARSE) h2[t] = 0;
        __syncthreads();

        const int2 c2 = *(const int2*)&col[e0];
        const int2 r2 = *(const int2*)&row[e0];
        const float2 w2 = *(const float2*)&ew[e0];
        const int cc[2] = {c2.x >> 8, c2.y >> 8};

        atomicAdd(&h2[cc[0]], 1);
        atomicAdd(&h2[cc[1]], 1);
        __syncthreads();

        const int myc = (t < NCOARSE) ? h2[t] : 0;
        if (t < NCOARSE) off[t] = myc;
        __syncthreads();
        scan256_wave(off, wsum, t);               // inclusive, 2 syncs
        if (t < NCOARSE) {
            off[t] -= myc;                        // exclusive
            base_blk[t] = myc ? atomicAdd(&cursor[t], myc) : 0;
            h2[t] = 0;
        }
        __syncthreads();

        const int fi[2] = {c2.x & 255, c2.y & 255};
        const int rr[2] = {r2.x, r2.y};
        const float wv[2] = {w2.x, w2.y};
#pragma unroll
        for (int j = 0; j < 2; ++j) {
            const int c = cc[j];
            const int r = atomicAdd(&h2[c], 1);
            const int s = off[c] + r;
            const int bp = base_blk[c] + r;
            stg[s] = make_int2((rr[j] << 8) | fi[j], __float_as_int(wv[j]));
            gpA[s] = (bp < SEGCAP) ? (c * SEGCAP + bp) : -1;
        }
        __syncthreads();
        for (int i = t; i < P3CHUNK; i += 1024) { // sorted order -> run-coalesced
            const int gp = gpA[i];
            if (gp >= 0) csr_tmp[gp] = stg[i];
        }
    } else {
        // ---- gemm block: 64 rows, hb = bf16(x @ W1) ----
        float* Ws = (float*)sm;                   // 16 KB
        float* Xs = (float*)(sm + 16384);         // 16 KB: [64][64]
        const int row0 = (b - b / 3) * 64;
        for (int i = t; i < DIM * DIM; i += 1024) Ws[i] = W[i];
        for (int i = t; i < 64 * DIM; i += 1024)
            Xs[i] = x[(size_t)row0 * DIM + i];
        __syncthreads();
        const int j = t & 63;
        const int rs = t >> 6;                    // 0..15
        for (int rrr = 0; rrr < 4; ++rrr) {
            const int r = rs * 4 + rrr;
            float acc = 0.f;
#pragma unroll
            for (int k = 0; k < DIM; ++k) acc += Xs[r * DIM + k] * Ws[k * DIM + j];
            hb[(size_t)(row0 + r) * DIM + j] = (u16)f2bf(acc);
        }
    }
}

// ---------------- P4: fine sort + dinv + rowptr + premult; 4B csr out -------
// Inlined cursor scan; wave-shuffle scans. csr = {bf16(ew*dv_dst)<<16 | src}

__global__ __launch_bounds__(512) void p4_fine(const int* __restrict__ cursor,
                                               const int2* __restrict__ csr_tmp,
                                               u32* __restrict__ csr,
                                               int* __restrict__ rowptr,
                                               float* __restrict__ dinv,
                                               u16* __restrict__ hb) {
    __shared__ int2 A[SEGCAP];          // 40 KB
    __shared__ u32 Bu[SEGCAP];          // 20 KB
    __shared__ int fh[NCOARSE];
    __shared__ int off2[NCOARSE];
    __shared__ int cbase[NCOARSE];
    __shared__ float degw[NCOARSE];
    __shared__ float dvs[NCOARSE];
    __shared__ int wsum[4];
    const int t = threadIdx.x;
    const int c = blockIdx.x;
    const int segN = min(cursor[c], SEGCAP);

    // inclusive scan of clamped cursors -> output base for bucket c
    if (t < NCOARSE) cbase[t] = min(cursor[t], SEGCAP);
    __syncthreads();
    scan256_wave(cbase, wsum, t);
    const int seg0_out = cbase[c] - segN;

    for (int i = t; i < segN; i += 512) A[i] = csr_tmp[c * SEGCAP + i];
    if (t < NCOARSE) { fh[t] = 0; degw[t] = 0.f; }
    __syncthreads();

    for (int i = t; i < segN; i += 512) {
        const int f = A[i].x & 255;
        atomicAdd(&fh[f], 1);
        atomicAdd(&degw[f], __int_as_float(A[i].y));
    }
    __syncthreads();

    if (t < NCOARSE) off2[t] = fh[t];
    __syncthreads();
    scan256_wave(off2, wsum, t);
    if (t < NCOARSE) {
        off2[t] -= fh[t];                         // exclusive
        const float dv = rsqrtf(1.0f + degw[t]);
        dvs[t] = dv;
        dinv[c * 256 + t] = dv;
        rowptr[c * 256 + t] = seg0_out + off2[t];
        fh[t] = 0;                                // reset for rank pass
    }
    if (c == NCOARSE - 1 && t == 0) rowptr[N_NODES] = seg0_out + segN;
    __syncthreads();

    // premultiply hb rows of this bucket's 256 nodes by their dinv
    for (int idx = t; idx < 256 * 8; idx += 512) {
        const int nl = idx >> 3;
        const int part = idx & 7;
        const float dv = dvs[nl];
        const size_t p = (size_t)(c * 256 + nl) * DIM + part * 8;
        uint4 v = *(const uint4*)&hb[p];
        uint4 o;
        o.x = f2bf(dv * bf2f(v.x & 0xffff)) | (f2bf(dv * bf2f(v.x >> 16)) << 16);
        o.y = f2bf(dv * bf2f(v.y & 0xffff)) | (f2bf(dv * bf2f(v.y >> 16)) << 16);
        o.z = f2bf(dv * bf2f(v.z & 0xffff)) | (f2bf(dv * bf2f(v.z >> 16)) << 16);
        o.w = f2bf(dv * bf2f(v.w & 0xffff)) | (f2bf(dv * bf2f(v.w >> 16)) << 16);
        *(uint4*)&hb[p] = o;
    }

    for (int i = t; i < segN; i += 512) {
        const int f = A[i].x & 255;
        const int r = atomicAdd(&fh[f], 1);
        const float w = __int_as_float(A[i].y) * dvs[f];
        Bu[off2[f] + r] = (f2bf(w) << 16) | ((u32)(A[i].x >> 8) & 0xffffu);
    }
    __syncthreads();
    for (int i = t; i < segN; i += 512)           // fully coalesced
        csr[seg0_out + i] = Bu[i];
}

// ---------------- aggregate layer 1 (4B csr; premult tables) ----------------
// h1p = bf16( dv * ( sum(w_e * hb2[src_e]) + dv*hb2[node] + bias ) )

__global__ __launch_bounds__(256) void aggregate_l1(const int* __restrict__ rowptr,
                                                    const u32* __restrict__ csr,
                                                    const u16* __restrict__ hb2,
                                                    const float* __restrict__ dinv,
                                                    const float* __restrict__ bias,
                                                    u16* __restrict__ ob) {
    const int lane = threadIdx.x & 63;
    const int node = (blockIdx.x * 256 + threadIdx.x) >> 6;
    const int g = lane >> 3;
    const int q = lane & 7;
    const int start = rowptr[node];
    const int end = rowptr[node + 1];
    const float dv = dinv[node];

    float acc[8];
#pragma unroll
    for (int k = 0; k < 8; ++k) acc[k] = 0.f;

    for (int i = start; i < end; i += 16) {
        const int i0 = i + g;
        const int i1 = i + 8 + g;
        const u32 v0 = (i0 < end) ? csr[i0] : 0;
        const u32 v1 = (i1 < end) ? csr[i1] : 0;
        const float w0 = bf2f(v0 >> 16);
        const float w1 = bf2f(v1 >> 16);
        const uint4 B0 = *(const uint4*)&hb2[(size_t)(v0 & 0xffffu) * DIM + q * 8];
        const uint4 B1 = *(const uint4*)&hb2[(size_t)(v1 & 0xffffu) * DIM + q * 8];
        acc[0] += w0 * bf2f(B0.x & 0xffff) + w1 * bf2f(B1.x & 0xffff);
        acc[1] += w0 * bf2f(B0.x >> 16)    + w1 * bf2f(B1.x >> 16);
        acc[2] += w0 * bf2f(B0.y & 0xffff) + w1 * bf2f(B1.y & 0xffff);
        acc[3] += w0 * bf2f(B0.y >> 16)    + w1 * bf2f(B1.y >> 16);
        acc[4] += w0 * bf2f(B0.z & 0xffff) + w1 * bf2f(B1.z & 0xffff);
        acc[5] += w0 * bf2f(B0.z >> 16)    + w1 * bf2f(B1.z >> 16);
        acc[6] += w0 * bf2f(B0.w & 0xffff) + w1 * bf2f(B1.w & 0xffff);
        acc[7] += w0 * bf2f(B0.w >> 16)    + w1 * bf2f(B1.w >> 16);
    }
#pragma unroll
    for (int m = 8; m <= 32; m <<= 1) {
#pragma unroll
        for (int k = 0; k < 8; ++k) acc[k] += __shfl_xor(acc[k], m, 64);
    }
    if (lane < 8) {
        const uint4 S = *(const uint4*)&hb2[(size_t)node * DIM + q * 8];
        float r[8];
        r[0] = dv * (acc[0] + dv * bf2f(S.x & 0xffff) + bias[q * 8 + 0]);
        r[1] = dv * (acc[1] + dv * bf2f(S.x >> 16)    + bias[q * 8 + 1]);
        r[2] = dv * (acc[2] + dv * bf2f(S.y & 0xffff) + bias[q * 8 + 2]);
        r[3] = dv * (acc[3] + dv * bf2f(S.y >> 16)    + bias[q * 8 + 3]);
        r[4] = dv * (acc[4] + dv * bf2f(S.z & 0xffff) + bias[q * 8 + 4]);
        r[5] = dv * (acc[5] + dv * bf2f(S.z >> 16)    + bias[q * 8 + 5]);
        r[6] = dv * (acc[6] + dv * bf2f(S.w & 0xffff) + bias[q * 8 + 6]);
        r[7] = dv * (acc[7] + dv * bf2f(S.w >> 16)    + bias[q * 8 + 7]);
        uint4 o;
        o.x = f2bf(r[0]) | (f2bf(r[1]) << 16);
        o.y = f2bf(r[2]) | (f2bf(r[3]) << 16);
        o.z = f2bf(r[4]) | (f2bf(r[5]) << 16);
        o.w = f2bf(r[6]) | (f2bf(r[7]) << 16);
        *(uint4*)&ob[(size_t)node * DIM + q * 8] = o;
    }
}

// ---------------- fused: layer-2 aggregate + pool + W2 GEMM (flat range) ----

__global__ __launch_bounds__(512) void agg2_pool_gemm(const int* __restrict__ rowptr,
                                                      const u32* __restrict__ csr,
                                                      const u16* __restrict__ hb,
                                                      const float* __restrict__ dinv,
                                                      const float* __restrict__ W2,
                                                      const float* __restrict__ b2,
                                                      float* __restrict__ out) {
    __shared__ float Ws[DIM * DIM];
    __shared__ float wacc[8][DIM];
    __shared__ float pooled[DIM];
    const int t = threadIdx.x;
    const int m = blockIdx.x;

    for (int i = t; i < DIM * DIM; i += 512) Ws[i] = W2[i];

    const int wave = t >> 6;
    const int lane = t & 63;
    const int g = lane >> 3;
    const int q = lane & 7;

    const int start = rowptr[m * 64];
    const int end = rowptr[m * 64 + 64];

    float acc[8];
#pragma unroll
    for (int k = 0; k < 8; ++k) acc[k] = 0.f;

    for (int i = start + wave * 32; i < end; i += 256) {
        const int i0 = i + g;
        const int i1 = i + 8 + g;
        const int i2 = i + 16 + g;
        const int i3 = i + 24 + g;
        const u32 v0 = (i0 < end) ? csr[i0] : 0;
        const u32 v1 = (i1 < end) ? csr[i1] : 0;
        const u32 v2 = (i2 < end) ? csr[i2] : 0;
        const u32 v3 = (i3 < end) ? csr[i3] : 0;
        const float w0 = bf2f(v0 >> 16);
        const float w1 = bf2f(v1 >> 16);
        const float w2 = bf2f(v2 >> 16);
        const float w3 = bf2f(v3 >> 16);
        const uint4 B0 = *(const uint4*)&hb[(size_t)(v0 & 0xffffu) * DIM + q * 8];
        const uint4 B1 = *(const uint4*)&hb[(size_t)(v1 & 0xffffu) * DIM + q * 8];
        const uint4 B2 = *(const uint4*)&hb[(size_t)(v2 & 0xffffu) * DIM + q * 8];
        const uint4 B3 = *(const uint4*)&hb[(size_t)(v3 & 0xffffu) * DIM + q * 8];
        acc[0] += w0 * bf2f(B0.x & 0xffff) + w1 * bf2f(B1.x & 0xffff)
                + w2 * bf2f(B2.x & 0xffff) + w3 * bf2f(B3.x & 0xffff);
        acc[1] += w0 * bf2f(B0.x >> 16)    + w1 * bf2f(B1.x >> 16)
                + w2 * bf2f(B2.x >> 16)    + w3 * bf2f(B3.x >> 16);
        acc[2] += w0 * bf2f(B0.y & 0xffff) + w1 * bf2f(B1.y & 0xffff)
                + w2 * bf2f(B2.y & 0xffff) + w3 * bf2f(B3.y & 0xffff);
        acc[3] += w0 * bf2f(B0.y >> 16)    + w1 * bf2f(B1.y >> 16)
                + w2 * bf2f(B2.y >> 16)    + w3 * bf2f(B3.y >> 16);
        acc[4] += w0 * bf2f(B0.z & 0xffff) + w1 * bf2f(B1.z & 0xffff)
                + w2 * bf2f(B2.z & 0xffff) + w3 * bf2f(B3.z & 0xffff);
        acc[5] += w0 * bf2f(B0.z >> 16)    + w1 * bf2f(B1.z >> 16)
                + w2 * bf2f(B2.z >> 16)    + w3 * bf2f(B3.z >> 16);
        acc[6] += w0 * bf2f(B0.w & 0xffff) + w1 * bf2f(B1.w & 0xffff)
                + w2 * bf2f(B2.w & 0xffff) + w3 * bf2f(B3.w & 0xffff);
        acc[7] += w0 * bf2f(B0.w >> 16)    + w1 * bf2f(B1.w >> 16)
                + w2 * bf2f(B2.w >> 16)    + w3 * bf2f(B3.w >> 16);
    }

    // self terms: wave handles nodes m*64 + wave*8 + g (each exactly once)
    {
        const int node = m * 64 + wave * 8 + g;
        const float dv = dinv[node];
        const uint4 S = *(const uint4*)&hb[(size_t)node * DIM + q * 8];
        acc[0] += dv * bf2f(S.x & 0xffff);
        acc[1] += dv * bf2f(S.x >> 16);
        acc[2] += dv * bf2f(S.y & 0xffff);
        acc[3] += dv * bf2f(S.y >> 16);
        acc[4] += dv * bf2f(S.z & 0xffff);
        acc[5] += dv * bf2f(S.z >> 16);
        acc[6] += dv * bf2f(S.w & 0xffff);
        acc[7] += dv * bf2f(S.w >> 16);
    }

#pragma unroll
    for (int mm = 8; mm <= 32; mm <<= 1) {
#pragma unroll
        for (int k = 0; k < 8; ++k) acc[k] += __shfl_xor(acc[k], mm, 64);
    }
    if (lane < 8) {
#pragma unroll
        for (int k = 0; k < 8; ++k) wacc[wave][q * 8 + k] = acc[k];
    }
    __syncthreads();
    if (t < DIM) {
        float p = 0.f;
#pragma unroll
        for (int w = 0; w < 8; ++w) p += wacc[w][t];
        pooled[t] = p * (1.0f / DIM);
    }
    __syncthreads();
    if (t < DIM) {
        float o = b2[t];
#pragma unroll
        for (int k = 0; k < DIM; ++k) o += pooled[k] * Ws[k * DIM + t];
        out[(size_t)t * M_POOL + m] = o;
    }
}

// ---------------- launcher --------------------------------------------------

extern "C" void kernel_launch(void* const* d_in, const int* in_sizes, int n_in,
                              void* d_out, int out_size, void* d_ws, size_t ws_size,
                              hipStream_t stream) {
    const float* x  = (const float*)d_in[0];
    const int*   ei = (const int*)d_in[1];   // [2][E]
    const float* ew = (const float*)d_in[2];
    const float* W1 = (const float*)d_in[3];
    const float* b1 = (const float*)d_in[4];
    const float* W2 = (const float*)d_in[5];
    const float* b2 = (const float*)d_in[6];
    float* out = (float*)d_out;

    char* w = (char*)d_ws;
    int*   cursor = (int*)w;   w += 1024;
    int*   rowptr = (int*)w;   w += (size_t)(N_NODES + 16) * 4;      // 0.25 MB
    float* dinv   = (float*)w; w += (size_t)N_NODES * 4;             // 0.25 MB
    int2*  csrt   = (int2*)w;  w += (size_t)NCOARSE * SEGCAP * 8;    // 10.5 MB
    u32*   csr    = (u32*)w;   w += (size_t)N_EDGES * 4;             // 4 MB
    u16*   hbf    = (u16*)w;   w += (size_t)N_NODES * DIM * 2;       // 8 MB
    u16*   h1bf   = (u16*)w;                                         // 8 MB

    const int* row = ei;             // edge_index[0]
    const int* col = ei + N_EDGES;   // edge_index[1]

    // build: gemm || coarse-multisplit in one grid, then fine sort (+scan inlined)
    zero_cursor<<<1, 256, 0, stream>>>(cursor);
    fused_gemm_p3<<<FUSED_BLOCKS, 1024, 0, stream>>>(x, W1, hbf, col, row, ew,
                                                     cursor, csrt);
    p4_fine<<<NCOARSE, 512, 0, stream>>>(cursor, csrt, csr, rowptr, dinv, hbf);

    // layer 1 aggregate: h1p = bf16(dv * (A h + b1))   (premultiplied)
    aggregate_l1<<<N_NODES / 4, 256, 0, stream>>>(rowptr, csr, hbf, dinv, b1, h1bf);

    // layer 2 + pool + W2-GEMM fused per window (flat contiguous edge range)
    agg2_pool_gemm<<<M_POOL, 512, 0, stream>>>(rowptr, csr, h1bf, dinv, W2, b2, out);
}

// Round 15
// 116.475 us; speedup vs baseline: 1.0614x; 1.0614x over previous
//
#include <hip/hip_runtime.h>

#define N_NODES 65536
#define N_EDGES 1048576
#define DIM 64
#define M_POOL (N_NODES / DIM)  // 1024
#define NCOARSE 256             // coarse buckets (col>>8), 256 nodes each
#define SEGCAP 5120             // fixed region per coarse bucket (mean 4096 + 16 sigma)
#define P3CHUNK 1024            // edges per p3 block (4/thread @ 256 thr)
#define P3BLOCKS (N_EDGES / P3CHUNK)   // 1024
#define GEMM_ROWS 32
#define GEMM_BLOCKS (N_NODES / GEMM_ROWS)      // 2048
#define FUSED_BLOCKS (GEMM_BLOCKS + P3BLOCKS)  // 3072, 2:1 interleave

typedef unsigned int u32;
typedef unsigned short u16;

__device__ __forceinline__ float bf2f(u32 hi16) {
    return __uint_as_float(hi16 << 16);
}
__device__ __forceinline__ u32 f2bf(float f) {  // RNE
    u32 u = __float_as_uint(f);
    return (u + 0x7fffu + ((u >> 16) & 1u)) >> 16;
}

// inclusive scan of arr[256] by threads t<256 (4 full waves), 2 syncs.
__device__ __forceinline__ void scan256_wave(int* arr, int* wsum, int t) {
    int s = 0;
    if (t < 256) {
        s = arr[t];
        const int lane = t & 63;
#pragma unroll
        for (int o = 1; o < 64; o <<= 1) {
            const int u = __shfl_up(s, o, 64);
            if (lane >= o) s += u;
        }
        if (lane == 63) wsum[t >> 6] = s;
    }
    __syncthreads();
    if (t < 256) {
        const int w = t >> 6;
        int add = 0;
#pragma unroll
        for (int k = 0; k < 4; ++k)
            if (k < w) add += wsum[k];
        arr[t] = s + add;
    }
    __syncthreads();
}

// ---------------- zero the 256 coarse cursors ----------------

__global__ __launch_bounds__(256) void zero_cursor(int* __restrict__ cursor) {
    cursor[threadIdx.x] = 0;
}

// ---------------- fused: layer-1 GEMM || coarse multisplit (direct write) ---
// 3072 blocks x 256 thr. b%3==2 -> p3 chunk b/3 (1024 edges, direct global
// scatter, no LDS staging); else gemm tile (b - b/3)*32 rows.

__global__ __launch_bounds__(256) void fused_gemm_p3(const float* __restrict__ x,
                                                     const float* __restrict__ W,
                                                     u16* __restrict__ hb,
                                                     const int* __restrict__ col,
                                                     const int* __restrict__ row,
                                                     const float* __restrict__ ew,
                                                     int* __restrict__ cursor,
                                                     int2* __restrict__ csr_tmp) {
    __shared__ __align__(16) char sm[24832];
    const int t = threadIdx.x;
    const int b = blockIdx.x;

    if ((b % 3) == 2) {
        // ---- p3 block: coarse multisplit of chunk b/3, direct writes ----
        int* h2       = (int*)sm;                 // 1024 B
        int* off      = (int*)(sm + 1024);        // 1024 B
        int* base_blk = (int*)(sm + 2048);        // 1024 B
        int* wsum     = (int*)(sm + 3072);        //   16 B
        const int e0 = (b / 3) * P3CHUNK + t * 4;

        h2[t] = 0;
        __syncthreads();

        const int4 c4 = *(const int4*)&col[e0];
        const int4 r4 = *(const int4*)&row[e0];
        const float4 w4 = *(const float4*)&ew[e0];
        const int cc[4] = {c4.x >> 8, c4.y >> 8, c4.z >> 8, c4.w >> 8};

        atomicAdd(&h2[cc[0]], 1);
        atomicAdd(&h2[cc[1]], 1);
        atomicAdd(&h2[cc[2]], 1);
        atomicAdd(&h2[cc[3]], 1);
        __syncthreads();

        const int myc = h2[t];
        off[t] = myc;
        __syncthreads();
        scan256_wave(off, wsum, t);               // inclusive, 2 syncs
        off[t] -= myc;                            // exclusive (own slot)
        base_blk[t] = myc ? atomicAdd(&cursor[t], myc) : 0;
        h2[t] = 0;
        __syncthreads();

        const int fi[4] = {c4.x & 255, c4.y & 255, c4.z & 255, c4.w & 255};
        const int rr[4] = {r4.x, r4.y, r4.z, r4.w};
        const float wv[4] = {w4.x, w4.y, w4.z, w4.w};
#pragma unroll
        for (int j = 0; j < 4; ++j) {
            const int c = cc[j];
            const int r = atomicAdd(&h2[c], 1);
            const int bp = base_blk[c] + r;
            if (bp < SEGCAP)
                csr_tmp[c * SEGCAP + bp] =
                    make_int2((rr[j] << 8) | fi[j], __float_as_int(wv[j]));
        }
    } else {
        // ---- gemm block: 32 rows, hb = bf16(x @ W1) ----
        float* Ws = (float*)sm;                   // 16 KB
        float* Xs = (float*)(sm + 16384);         //  8 KB: [32][64]
        const int row0 = (b - b / 3) * GEMM_ROWS;
        for (int i = t; i < DIM * DIM; i += 256) Ws[i] = W[i];
        for (int i = t; i < GEMM_ROWS * DIM; i += 256)
            Xs[i] = x[(size_t)row0 * DIM + i];
        __syncthreads();
        const int j = t & 63;
        const int rs = t >> 6;                    // 0..3
        for (int rrr = 0; rrr < 8; ++rrr) {
            const int r = rs * 8 + rrr;
            float acc = 0.f;
#pragma unroll
            for (int k = 0; k < DIM; ++k) acc += Xs[r * DIM + k] * Ws[k * DIM + j];
            hb[(size_t)(row0 + r) * DIM + j] = (u16)f2bf(acc);
        }
    }
}

// ---------------- P4: fine sort + dinv + rowptr + premult; 4B csr out -------
// Inlined cursor scan; wave-shuffle scans. csr = {bf16(ew*dv_dst)<<16 | src}

__global__ __launch_bounds__(512) void p4_fine(const int* __restrict__ cursor,
                                               const int2* __restrict__ csr_tmp,
                                               u32* __restrict__ csr,
                                               int* __restrict__ rowptr,
                                               float* __restrict__ dinv,
                                               u16* __restrict__ hb) {
    __shared__ int2 A[SEGCAP];          // 40 KB
    __shared__ u32 Bu[SEGCAP];          // 20 KB
    __shared__ int fh[NCOARSE];
    __shared__ int off2[NCOARSE];
    __shared__ int cbase[NCOARSE];
    __shared__ float degw[NCOARSE];
    __shared__ float dvs[NCOARSE];
    __shared__ int wsum[4];
    const int t = threadIdx.x;
    const int c = blockIdx.x;
    const int segN = min(cursor[c], SEGCAP);

    // inclusive scan of clamped cursors -> output base for bucket c
    if (t < NCOARSE) cbase[t] = min(cursor[t], SEGCAP);
    __syncthreads();
    scan256_wave(cbase, wsum, t);
    const int seg0_out = cbase[c] - segN;

    for (int i = t; i < segN; i += 512) A[i] = csr_tmp[c * SEGCAP + i];
    if (t < NCOARSE) { fh[t] = 0; degw[t] = 0.f; }
    __syncthreads();

    for (int i = t; i < segN; i += 512) {
        const int f = A[i].x & 255;
        atomicAdd(&fh[f], 1);
        atomicAdd(&degw[f], __int_as_float(A[i].y));
    }
    __syncthreads();

    if (t < NCOARSE) off2[t] = fh[t];
    __syncthreads();
    scan256_wave(off2, wsum, t);
    if (t < NCOARSE) {
        off2[t] -= fh[t];                         // exclusive
        const float dv = rsqrtf(1.0f + degw[t]);
        dvs[t] = dv;
        dinv[c * 256 + t] = dv;
        rowptr[c * 256 + t] = seg0_out + off2[t];
        fh[t] = 0;                                // reset for rank pass
    }
    if (c == NCOARSE - 1 && t == 0) rowptr[N_NODES] = seg0_out + segN;
    __syncthreads();

    // premultiply hb rows of this bucket's 256 nodes by their dinv
    for (int idx = t; idx < 256 * 8; idx += 512) {
        const int nl = idx >> 3;
        const int part = idx & 7;
        const float dv = dvs[nl];
        const size_t p = (size_t)(c * 256 + nl) * DIM + part * 8;
        uint4 v = *(const uint4*)&hb[p];
        uint4 o;
        o.x = f2bf(dv * bf2f(v.x & 0xffff)) | (f2bf(dv * bf2f(v.x >> 16)) << 16);
        o.y = f2bf(dv * bf2f(v.y & 0xffff)) | (f2bf(dv * bf2f(v.y >> 16)) << 16);
        o.z = f2bf(dv * bf2f(v.z & 0xffff)) | (f2bf(dv * bf2f(v.z >> 16)) << 16);
        o.w = f2bf(dv * bf2f(v.w & 0xffff)) | (f2bf(dv * bf2f(v.w >> 16)) << 16);
        *(uint4*)&hb[p] = o;
    }

    for (int i = t; i < segN; i += 512) {
        const int f = A[i].x & 255;
        const int r = atomicAdd(&fh[f], 1);
        const float w = __int_as_float(A[i].y) * dvs[f];
        Bu[off2[f] + r] = (f2bf(w) << 16) | ((u32)(A[i].x >> 8) & 0xffffu);
    }
    __syncthreads();
    for (int i = t; i < segN; i += 512)           // fully coalesced
        csr[seg0_out + i] = Bu[i];
}

// ---------------- aggregate layer 1 (4B csr; premult tables) ----------------
// h1p = bf16( dv * ( sum(w_e * hb2[src_e]) + dv*hb2[node] + bias ) )

__global__ __launch_bounds__(256) void aggregate_l1(const int* __restrict__ rowptr,
                                                    const u32* __restrict__ csr,
                                                    const u16* __restrict__ hb2,
                                                    const float* __restrict__ dinv,
                                                    const float* __restrict__ bias,
                                                    u16* __restrict__ ob) {
    const int lane = threadIdx.x & 63;
    const int node = (blockIdx.x * 256 + threadIdx.x) >> 6;
    const int g = lane >> 3;
    const int q = lane & 7;
    const int start = rowptr[node];
    const int end = rowptr[node + 1];
    const float dv = dinv[node];

    float acc[8];
#pragma unroll
    for (int k = 0; k < 8; ++k) acc[k] = 0.f;

    for (int i = start; i < end; i += 16) {
        const int i0 = i + g;
        const int i1 = i + 8 + g;
        const u32 v0 = (i0 < end) ? csr[i0] : 0;
        const u32 v1 = (i1 < end) ? csr[i1] : 0;
        const float w0 = bf2f(v0 >> 16);
        const float w1 = bf2f(v1 >> 16);
        const uint4 B0 = *(const uint4*)&hb2[(size_t)(v0 & 0xffffu) * DIM + q * 8];
        const uint4 B1 = *(const uint4*)&hb2[(size_t)(v1 & 0xffffu) * DIM + q * 8];
        acc[0] += w0 * bf2f(B0.x & 0xffff) + w1 * bf2f(B1.x & 0xffff);
        acc[1] += w0 * bf2f(B0.x >> 16)    + w1 * bf2f(B1.x >> 16);
        acc[2] += w0 * bf2f(B0.y & 0xffff) + w1 * bf2f(B1.y & 0xffff);
        acc[3] += w0 * bf2f(B0.y >> 16)    + w1 * bf2f(B1.y >> 16);
        acc[4] += w0 * bf2f(B0.z & 0xffff) + w1 * bf2f(B1.z & 0xffff);
        acc[5] += w0 * bf2f(B0.z >> 16)    + w1 * bf2f(B1.z >> 16);
        acc[6] += w0 * bf2f(B0.w & 0xffff) + w1 * bf2f(B1.w & 0xffff);
        acc[7] += w0 * bf2f(B0.w >> 16)    + w1 * bf2f(B1.w >> 16);
    }
#pragma unroll
    for (int m = 8; m <= 32; m <<= 1) {
#pragma unroll
        for (int k = 0; k < 8; ++k) acc[k] += __shfl_xor(acc[k], m, 64);
    }
    if (lane < 8) {
        const uint4 S = *(const uint4*)&hb2[(size_t)node * DIM + q * 8];
        float r[8];
        r[0] = dv * (acc[0] + dv * bf2f(S.x & 0xffff) + bias[q * 8 + 0]);
        r[1] = dv * (acc[1] + dv * bf2f(S.x >> 16)    + bias[q * 8 + 1]);
        r[2] = dv * (acc[2] + dv * bf2f(S.y & 0xffff) + bias[q * 8 + 2]);
        r[3] = dv * (acc[3] + dv * bf2f(S.y >> 16)    + bias[q * 8 + 3]);
        r[4] = dv * (acc[4] + dv * bf2f(S.z & 0xffff) + bias[q * 8 + 4]);
        r[5] = dv * (acc[5] + dv * bf2f(S.z >> 16)    + bias[q * 8 + 5]);
        r[6] = dv * (acc[6] + dv * bf2f(S.w & 0xffff) + bias[q * 8 + 6]);
        r[7] = dv * (acc[7] + dv * bf2f(S.w >> 16)    + bias[q * 8 + 7]);
        uint4 o;
        o.x = f2bf(r[0]) | (f2bf(r[1]) << 16);
        o.y = f2bf(r[2]) | (f2bf(r[3]) << 16);
        o.z = f2bf(r[4]) | (f2bf(r[5]) << 16);
        o.w = f2bf(r[6]) | (f2bf(r[7]) << 16);
        *(uint4*)&ob[(size_t)node * DIM + q * 8] = o;
    }
}

// ---------------- fused: layer-2 aggregate + pool + W2 GEMM (flat range) ----

__global__ __launch_bounds__(512) void agg2_pool_gemm(const int* __restrict__ rowptr,
                                                      const u32* __restrict__ csr,
                                                      const u16* __restrict__ hb,
                                                      const float* __restrict__ dinv,
                                                      const float* __restrict__ W2,
                                                      const float* __restrict__ b2,
                                                      float* __restrict__ out) {
    __shared__ float Ws[DIM * DIM];
    __shared__ float wacc[8][DIM];
    __shared__ float pooled[DIM];
    const int t = threadIdx.x;
    const int m = blockIdx.x;

    for (int i = t; i < DIM * DIM; i += 512) Ws[i] = W2[i];

    const int wave = t >> 6;
    const int lane = t & 63;
    const int g = lane >> 3;
    const int q = lane & 7;

    const int start = rowptr[m * 64];
    const int end = rowptr[m * 64 + 64];

    float acc[8];
#pragma unroll
    for (int k = 0; k < 8; ++k) acc[k] = 0.f;

    for (int i = start + wave * 32; i < end; i += 256) {
        const int i0 = i + g;
        const int i1 = i + 8 + g;
        const int i2 = i + 16 + g;
        const int i3 = i + 24 + g;
        const u32 v0 = (i0 < end) ? csr[i0] : 0;
        const u32 v1 = (i1 < end) ? csr[i1] : 0;
        const u32 v2 = (i2 < end) ? csr[i2] : 0;
        const u32 v3 = (i3 < end) ? csr[i3] : 0;
        const float w0 = bf2f(v0 >> 16);
        const float w1 = bf2f(v1 >> 16);
        const float w2 = bf2f(v2 >> 16);
        const float w3 = bf2f(v3 >> 16);
        const uint4 B0 = *(const uint4*)&hb[(size_t)(v0 & 0xffffu) * DIM + q * 8];
        const uint4 B1 = *(const uint4*)&hb[(size_t)(v1 & 0xffffu) * DIM + q * 8];
        const uint4 B2 = *(const uint4*)&hb[(size_t)(v2 & 0xffffu) * DIM + q * 8];
        const uint4 B3 = *(const uint4*)&hb[(size_t)(v3 & 0xffffu) * DIM + q * 8];
        acc[0] += w0 * bf2f(B0.x & 0xffff) + w1 * bf2f(B1.x & 0xffff)
                + w2 * bf2f(B2.x & 0xffff) + w3 * bf2f(B3.x & 0xffff);
        acc[1] += w0 * bf2f(B0.x >> 16)    + w1 * bf2f(B1.x >> 16)
                + w2 * bf2f(B2.x >> 16)    + w3 * bf2f(B3.x >> 16);
        acc[2] += w0 * bf2f(B0.y & 0xffff) + w1 * bf2f(B1.y & 0xffff)
                + w2 * bf2f(B2.y & 0xffff) + w3 * bf2f(B3.y & 0xffff);
        acc[3] += w0 * bf2f(B0.y >> 16)    + w1 * bf2f(B1.y >> 16)
                + w2 * bf2f(B2.y >> 16)    + w3 * bf2f(B3.y >> 16);
        acc[4] += w0 * bf2f(B0.z & 0xffff) + w1 * bf2f(B1.z & 0xffff)
                + w2 * bf2f(B2.z & 0xffff) + w3 * bf2f(B3.z & 0xffff);
        acc[5] += w0 * bf2f(B0.z >> 16)    + w1 * bf2f(B1.z >> 16)
                + w2 * bf2f(B2.z >> 16)    + w3 * bf2f(B3.z >> 16);
        acc[6] += w0 * bf2f(B0.w & 0xffff) + w1 * bf2f(B1.w & 0xffff)
                + w2 * bf2f(B2.w & 0xffff) + w3 * bf2f(B3.w & 0xffff);
        acc[7] += w0 * bf2f(B0.w >> 16)    + w1 * bf2f(B1.w >> 16)
                + w2 * bf2f(B2.w >> 16)    + w3 * bf2f(B3.w >> 16);
    }

    // self terms: wave handles nodes m*64 + wave*8 + g (each exactly once)
    {
        const int node = m * 64 + wave * 8 + g;
        const float dv = dinv[node];
        const uint4 S = *(const uint4*)&hb[(size_t)node * DIM + q * 8];
        acc[0] += dv * bf2f(S.x & 0xffff);
        acc[1] += dv * bf2f(S.x >> 16);
        acc[2] += dv * bf2f(S.y & 0xffff);
        acc[3] += dv * bf2f(S.y >> 16);
        acc[4] += dv * bf2f(S.z & 0xffff);
        acc[5] += dv * bf2f(S.z >> 16);
        acc[6] += dv * bf2f(S.w & 0xffff);
        acc[7] += dv * bf2f(S.w >> 16);
    }

#pragma unroll
    for (int mm = 8; mm <= 32; mm <<= 1) {
#pragma unroll
        for (int k = 0; k < 8; ++k) acc[k] += __shfl_xor(acc[k], mm, 64);
    }
    if (lane < 8) {
#pragma unroll
        for (int k = 0; k < 8; ++k) wacc[wave][q * 8 + k] = acc[k];
    }
    __syncthreads();
    if (t < DIM) {
        float p = 0.f;
#pragma unroll
        for (int w = 0; w < 8; ++w) p += wacc[w][t];
        pooled[t] = p * (1.0f / DIM);
    }
    __syncthreads();
    if (t < DIM) {
        float o = b2[t];
#pragma unroll
        for (int k = 0; k < DIM; ++k) o += pooled[k] * Ws[k * DIM + t];
        out[(size_t)t * M_POOL + m] = o;
    }
}

// ---------------- launcher --------------------------------------------------

extern "C" void kernel_launch(void* const* d_in, const int* in_sizes, int n_in,
                              void* d_out, int out_size, void* d_ws, size_t ws_size,
                              hipStream_t stream) {
    const float* x  = (const float*)d_in[0];
    const int*   ei = (const int*)d_in[1];   // [2][E]
    const float* ew = (const float*)d_in[2];
    const float* W1 = (const float*)d_in[3];
    const float* b1 = (const float*)d_in[4];
    const float* W2 = (const float*)d_in[5];
    const float* b2 = (const float*)d_in[6];
    float* out = (float*)d_out;

    char* w = (char*)d_ws;
    int*   cursor = (int*)w;   w += 1024;
    int*   rowptr = (int*)w;   w += (size_t)(N_NODES + 16) * 4;      // 0.25 MB
    float* dinv   = (float*)w; w += (size_t)N_NODES * 4;             // 0.25 MB
    int2*  csrt   = (int2*)w;  w += (size_t)NCOARSE * SEGCAP * 8;    // 10.5 MB
    u32*   csr    = (u32*)w;   w += (size_t)N_EDGES * 4;             // 4 MB
    u16*   hbf    = (u16*)w;   w += (size_t)N_NODES * DIM * 2;       // 8 MB
    u16*   h1bf   = (u16*)w;                                         // 8 MB

    const int* row = ei;             // edge_index[0]
    const int* col = ei + N_EDGES;   // edge_index[1]

    // build: gemm || coarse-multisplit in one grid, then fine sort (+scan inlined)
    zero_cursor<<<1, 256, 0, stream>>>(cursor);
    fused_gemm_p3<<<FUSED_BLOCKS, 256, 0, stream>>>(x, W1, hbf, col, row, ew,
                                                    cursor, csrt);
    p4_fine<<<NCOARSE, 512, 0, stream>>>(cursor, csrt, csr, rowptr, dinv, hbf);

    // layer 1 aggregate: h1p = bf16(dv * (A h + b1))   (premultiplied)
    aggregate_l1<<<N_NODES / 4, 256, 0, stream>>>(rowptr, csr, hbf, dinv, b1, h1bf);

    // layer 2 + pool + W2-GEMM fused per window (flat contiguous edge range)
    agg2_pool_gemm<<<M_POOL, 512, 0, stream>>>(rowptr, csr, h1bf, dinv, W2, b2, out);
}

// Round 16
// 113.570 us; speedup vs baseline: 1.0886x; 1.0256x over previous
//
#include <hip/hip_runtime.h>

#define N_NODES 65536
#define N_EDGES 1048576
#define DIM 64
#define M_POOL (N_NODES / DIM)  // 1024
#define NCOARSE 256             // coarse buckets (col>>8), 256 nodes each
#define SEGCAP 5120             // fixed region per coarse bucket (mean 4096 + 16 sigma)
#define P3CHUNK 1024            // edges per p3 block (4/thread @ 256 thr)
#define P3BLOCKS (N_EDGES / P3CHUNK)   // 1024
#define GEMM_ROWS 64
#define GEMM_BLOCKS (N_NODES / GEMM_ROWS)      // 1024
#define FUSED_BLOCKS (GEMM_BLOCKS + P3BLOCKS)  // 2048, 1:1 interleave

typedef unsigned int u32;
typedef unsigned short u16;

__device__ __forceinline__ float bf2f(u32 hi16) {
    return __uint_as_float(hi16 << 16);
}
__device__ __forceinline__ u32 f2bf(float f) {  // RNE
    u32 u = __float_as_uint(f);
    return (u + 0x7fffu + ((u >> 16) & 1u)) >> 16;
}

// inclusive scan of arr[256] by threads t<256 (4 full waves), 2 syncs.
__device__ __forceinline__ void scan256_wave(int* arr, int* wsum, int t) {
    int s = 0;
    if (t < 256) {
        s = arr[t];
        const int lane = t & 63;
#pragma unroll
        for (int o = 1; o < 64; o <<= 1) {
            const int u = __shfl_up(s, o, 64);
            if (lane >= o) s += u;
        }
        if (lane == 63) wsum[t >> 6] = s;
    }
    __syncthreads();
    if (t < 256) {
        const int w = t >> 6;
        int add = 0;
#pragma unroll
        for (int k = 0; k < 4; ++k)
            if (k < w) add += wsum[k];
        arr[t] = s + add;
    }
    __syncthreads();
}

// ---------------- zero the 256 coarse cursors ----------------

__global__ __launch_bounds__(256) void zero_cursor(int* __restrict__ cursor) {
    cursor[threadIdx.x] = 0;
}

// ---------------- fused: layer-1 GEMM (4x4 reg tile) || coarse multisplit ---
// 2048 blocks x 256 thr, 1:1. Even b -> gemm tile (b>>1)*64 rows; odd b -> p3
// chunk (b>>1) (1024 edges, direct global scatter).

__global__ __launch_bounds__(256) void fused_gemm_p3(const float* __restrict__ x,
                                                     const float* __restrict__ W,
                                                     u16* __restrict__ hb,
                                                     const int* __restrict__ col,
                                                     const int* __restrict__ row,
                                                     const float* __restrict__ ew,
                                                     int* __restrict__ cursor,
                                                     int2* __restrict__ csr_tmp) {
    __shared__ __align__(16) char sm[33808];
    const int t = threadIdx.x;
    const int b = blockIdx.x;

    if (b & 1) {
        // ---- p3 block: coarse multisplit of chunk b>>1, direct writes ----
        int* h2       = (int*)sm;                 // 1024 B
        int* off      = (int*)(sm + 1024);        // 1024 B
        int* base_blk = (int*)(sm + 2048);        // 1024 B
        int* wsum     = (int*)(sm + 3072);        //   16 B
        const int e0 = (b >> 1) * P3CHUNK + t * 4;

        h2[t] = 0;
        __syncthreads();

        const int4 c4 = *(const int4*)&col[e0];
        const int4 r4 = *(const int4*)&row[e0];
        const float4 w4 = *(const float4*)&ew[e0];
        const int cc[4] = {c4.x >> 8, c4.y >> 8, c4.z >> 8, c4.w >> 8};

        atomicAdd(&h2[cc[0]], 1);
        atomicAdd(&h2[cc[1]], 1);
        atomicAdd(&h2[cc[2]], 1);
        atomicAdd(&h2[cc[3]], 1);
        __syncthreads();

        const int myc = h2[t];
        off[t] = myc;
        __syncthreads();
        scan256_wave(off, wsum, t);               // inclusive, 2 syncs
        off[t] -= myc;                            // exclusive (own slot)
        base_blk[t] = myc ? atomicAdd(&cursor[t], myc) : 0;
        h2[t] = 0;
        __syncthreads();

        const int fi[4] = {c4.x & 255, c4.y & 255, c4.z & 255, c4.w & 255};
        const int rr[4] = {r4.x, r4.y, r4.z, r4.w};
        const float wv[4] = {w4.x, w4.y, w4.z, w4.w};
#pragma unroll
        for (int j = 0; j < 4; ++j) {
            const int c = cc[j];
            const int r = atomicAdd(&h2[c], 1);
            const int bp = base_blk[c] + r;
            if (bp < SEGCAP)
                csr_tmp[c * SEGCAP + bp] =
                    make_int2((rr[j] << 8) | fi[j], __float_as_int(wv[j]));
        }
    } else {
        // ---- gemm block: 64 rows x 64 cols, 4x4 register tile per thread ----
        float* Ws  = (float*)sm;                  // 16384 B: [64][64] k-major
        float* XsT = (float*)(sm + 16384);        // 17408 B: [64 k][68] (padded)
        const int row0 = (b >> 1) * GEMM_ROWS;
        for (int i = t; i < DIM * DIM; i += 256) Ws[i] = W[i];
        for (int i = t; i < GEMM_ROWS * DIM; i += 256) {
            const int r = i >> 6;
            const int k = i & 63;
            XsT[k * 68 + r] = x[(size_t)(row0 + r) * DIM + k];
        }
        __syncthreads();

        const int tr = t >> 4;    // 0..15 -> rows tr*4..+3
        const int tc = t & 15;    // 0..15 -> cols tc*4..+3
        float4 a0 = {0.f, 0.f, 0.f, 0.f};
        float4 a1 = a0, a2 = a0, a3 = a0;
#pragma unroll
        for (int k = 0; k < DIM; ++k) {
            const float4 xv = *(const float4*)&XsT[k * 68 + tr * 4];
            const float4 wv = *(const float4*)&Ws[k * DIM + tc * 4];
            a0.x += xv.x * wv.x; a0.y += xv.x * wv.y;
            a0.z += xv.x * wv.z; a0.w += xv.x * wv.w;
            a1.x += xv.y * wv.x; a1.y += xv.y * wv.y;
            a1.z += xv.y * wv.z; a1.w += xv.y * wv.w;
            a2.x += xv.z * wv.x; a2.y += xv.z * wv.y;
            a2.z += xv.z * wv.z; a2.w += xv.z * wv.w;
            a3.x += xv.w * wv.x; a3.y += xv.w * wv.y;
            a3.z += xv.w * wv.z; a3.w += xv.w * wv.w;
        }
        // store 4 rows x 4 cols as bf16 (8B per row-chunk)
        const size_t base = (size_t)(row0 + tr * 4) * DIM + tc * 4;
        ushort4 o;
        o.x = (u16)f2bf(a0.x); o.y = (u16)f2bf(a0.y);
        o.z = (u16)f2bf(a0.z); o.w = (u16)f2bf(a0.w);
        *(ushort4*)&hb[base] = o;
        o.x = (u16)f2bf(a1.x); o.y = (u16)f2bf(a1.y);
        o.z = (u16)f2bf(a1.z); o.w = (u16)f2bf(a1.w);
        *(ushort4*)&hb[base + DIM] = o;
        o.x = (u16)f2bf(a2.x); o.y = (u16)f2bf(a2.y);
        o.z = (u16)f2bf(a2.z); o.w = (u16)f2bf(a2.w);
        *(ushort4*)&hb[base + 2 * DIM] = o;
        o.x = (u16)f2bf(a3.x); o.y = (u16)f2bf(a3.y);
        o.z = (u16)f2bf(a3.z); o.w = (u16)f2bf(a3.w);
        *(ushort4*)&hb[base + 3 * DIM] = o;
    }
}

// ---------------- P4: fine sort + dinv + rowptr + premult; 4B csr out -------

__global__ __launch_bounds__(512) void p4_fine(const int* __restrict__ cursor,
                                               const int2* __restrict__ csr_tmp,
                                               u32* __restrict__ csr,
                                               int* __restrict__ rowptr,
                                               float* __restrict__ dinv,
                                               u16* __restrict__ hb) {
    __shared__ int2 A[SEGCAP];          // 40 KB
    __shared__ u32 Bu[SEGCAP];          // 20 KB
    __shared__ int fh[NCOARSE];
    __shared__ int off2[NCOARSE];
    __shared__ int cbase[NCOARSE];
    __shared__ float degw[NCOARSE];
    __shared__ float dvs[NCOARSE];
    __shared__ int wsum[4];
    const int t = threadIdx.x;
    const int c = blockIdx.x;
    const int segN = min(cursor[c], SEGCAP);

    // inclusive scan of clamped cursors -> output base for bucket c
    if (t < NCOARSE) cbase[t] = min(cursor[t], SEGCAP);
    __syncthreads();
    scan256_wave(cbase, wsum, t);
    const int seg0_out = cbase[c] - segN;

    for (int i = t; i < segN; i += 512) A[i] = csr_tmp[c * SEGCAP + i];
    if (t < NCOARSE) { fh[t] = 0; degw[t] = 0.f; }
    __syncthreads();

    for (int i = t; i < segN; i += 512) {
        const int f = A[i].x & 255;
        atomicAdd(&fh[f], 1);
        atomicAdd(&degw[f], __int_as_float(A[i].y));
    }
    __syncthreads();

    if (t < NCOARSE) off2[t] = fh[t];
    __syncthreads();
    scan256_wave(off2, wsum, t);
    if (t < NCOARSE) {
        off2[t] -= fh[t];                         // exclusive
        const float dv = rsqrtf(1.0f + degw[t]);
        dvs[t] = dv;
        dinv[c * 256 + t] = dv;
        rowptr[c * 256 + t] = seg0_out + off2[t];
        fh[t] = 0;                                // reset for rank pass
    }
    if (c == NCOARSE - 1 && t == 0) rowptr[N_NODES] = seg0_out + segN;
    __syncthreads();

    // premultiply hb rows of this bucket's 256 nodes by their dinv
    for (int idx = t; idx < 256 * 8; idx += 512) {
        const int nl = idx >> 3;
        const int part = idx & 7;
        const float dv = dvs[nl];
        const size_t p = (size_t)(c * 256 + nl) * DIM + part * 8;
        uint4 v = *(const uint4*)&hb[p];
        uint4 o;
        o.x = f2bf(dv * bf2f(v.x & 0xffff)) | (f2bf(dv * bf2f(v.x >> 16)) << 16);
        o.y = f2bf(dv * bf2f(v.y & 0xffff)) | (f2bf(dv * bf2f(v.y >> 16)) << 16);
        o.z = f2bf(dv * bf2f(v.z & 0xffff)) | (f2bf(dv * bf2f(v.z >> 16)) << 16);
        o.w = f2bf(dv * bf2f(v.w & 0xffff)) | (f2bf(dv * bf2f(v.w >> 16)) << 16);
        *(uint4*)&hb[p] = o;
    }

    for (int i = t; i < segN; i += 512) {
        const int f = A[i].x & 255;
        const int r = atomicAdd(&fh[f], 1);
        const float w = __int_as_float(A[i].y) * dvs[f];
        Bu[off2[f] + r] = (f2bf(w) << 16) | ((u32)(A[i].x >> 8) & 0xffffu);
    }
    __syncthreads();
    for (int i = t; i < segN; i += 512)           // fully coalesced
        csr[seg0_out + i] = Bu[i];
}

// ---------------- aggregate layer 1 (4B csr; premult tables) ----------------
// h1p = bf16( dv * ( sum(w_e * hb2[src_e]) + dv*hb2[node] + bias ) )

__global__ __launch_bounds__(256) void aggregate_l1(const int* __restrict__ rowptr,
                                                    const u32* __restrict__ csr,
                                                    const u16* __restrict__ hb2,
                                                    const float* __restrict__ dinv,
                                                    const float* __restrict__ bias,
                                                    u16* __restrict__ ob) {
    const int lane = threadIdx.x & 63;
    const int node = (blockIdx.x * 256 + threadIdx.x) >> 6;
    const int g = lane >> 3;
    const int q = lane & 7;
    const int start = rowptr[node];
    const int end = rowptr[node + 1];
    const float dv = dinv[node];

    float acc[8];
#pragma unroll
    for (int k = 0; k < 8; ++k) acc[k] = 0.f;

    for (int i = start; i < end; i += 16) {
        const int i0 = i + g;
        const int i1 = i + 8 + g;
        const u32 v0 = (i0 < end) ? csr[i0] : 0;
        const u32 v1 = (i1 < end) ? csr[i1] : 0;
        const float w0 = bf2f(v0 >> 16);
        const float w1 = bf2f(v1 >> 16);
        const uint4 B0 = *(const uint4*)&hb2[(size_t)(v0 & 0xffffu) * DIM + q * 8];
        const uint4 B1 = *(const uint4*)&hb2[(size_t)(v1 & 0xffffu) * DIM + q * 8];
        acc[0] += w0 * bf2f(B0.x & 0xffff) + w1 * bf2f(B1.x & 0xffff);
        acc[1] += w0 * bf2f(B0.x >> 16)    + w1 * bf2f(B1.x >> 16);
        acc[2] += w0 * bf2f(B0.y & 0xffff) + w1 * bf2f(B1.y & 0xffff);
        acc[3] += w0 * bf2f(B0.y >> 16)    + w1 * bf2f(B1.y >> 16);
        acc[4] += w0 * bf2f(B0.z & 0xffff) + w1 * bf2f(B1.z & 0xffff);
        acc[5] += w0 * bf2f(B0.z >> 16)    + w1 * bf2f(B1.z >> 16);
        acc[6] += w0 * bf2f(B0.w & 0xffff) + w1 * bf2f(B1.w & 0xffff);
        acc[7] += w0 * bf2f(B0.w >> 16)    + w1 * bf2f(B1.w >> 16);
    }
#pragma unroll
    for (int m = 8; m <= 32; m <<= 1) {
#pragma unroll
        for (int k = 0; k < 8; ++k) acc[k] += __shfl_xor(acc[k], m, 64);
    }
    if (lane < 8) {
        const uint4 S = *(const uint4*)&hb2[(size_t)node * DIM + q * 8];
        float r[8];
        r[0] = dv * (acc[0] + dv * bf2f(S.x & 0xffff) + bias[q * 8 + 0]);
        r[1] = dv * (acc[1] + dv * bf2f(S.x >> 16)    + bias[q * 8 + 1]);
        r[2] = dv * (acc[2] + dv * bf2f(S.y & 0xffff) + bias[q * 8 + 2]);
        r[3] = dv * (acc[3] + dv * bf2f(S.y >> 16)    + bias[q * 8 + 3]);
        r[4] = dv * (acc[4] + dv * bf2f(S.z & 0xffff) + bias[q * 8 + 4]);
        r[5] = dv * (acc[5] + dv * bf2f(S.z >> 16)    + bias[q * 8 + 5]);
        r[6] = dv * (acc[6] + dv * bf2f(S.w & 0xffff) + bias[q * 8 + 6]);
        r[7] = dv * (acc[7] + dv * bf2f(S.w >> 16)    + bias[q * 8 + 7]);
        uint4 o;
        o.x = f2bf(r[0]) | (f2bf(r[1]) << 16);
        o.y = f2bf(r[2]) | (f2bf(r[3]) << 16);
        o.z = f2bf(r[4]) | (f2bf(r[5]) << 16);
        o.w = f2bf(r[6]) | (f2bf(r[7]) << 16);
        *(uint4*)&ob[(size_t)node * DIM + q * 8] = o;
    }
}

// ---------------- fused: layer-2 aggregate + pool + W2 GEMM (flat range) ----

__global__ __launch_bounds__(512) void agg2_pool_gemm(const int* __restrict__ rowptr,
                                                      const u32* __restrict__ csr,
                                                      const u16* __restrict__ hb,
                                                      const float* __restrict__ dinv,
                                                      const float* __restrict__ W2,
                                                      const float* __restrict__ b2,
                                                      float* __restrict__ out) {
    __shared__ float Ws[DIM * DIM];
    __shared__ float wacc[8][DIM];
    __shared__ float pooled[DIM];
    const int t = threadIdx.x;
    const int m = blockIdx.x;

    for (int i = t; i < DIM * DIM; i += 512) Ws[i] = W2[i];

    const int wave = t >> 6;
    const int lane = t & 63;
    const int g = lane >> 3;
    const int q = lane & 7;

    const int start = rowptr[m * 64];
    const int end = rowptr[m * 64 + 64];

    float acc[8];
#pragma unroll
    for (int k = 0; k < 8; ++k) acc[k] = 0.f;

    for (int i = start + wave * 32; i < end; i += 256) {
        const int i0 = i + g;
        const int i1 = i + 8 + g;
        const int i2 = i + 16 + g;
        const int i3 = i + 24 + g;
        const u32 v0 = (i0 < end) ? csr[i0] : 0;
        const u32 v1 = (i1 < end) ? csr[i1] : 0;
        const u32 v2 = (i2 < end) ? csr[i2] : 0;
        const u32 v3 = (i3 < end) ? csr[i3] : 0;
        const float w0 = bf2f(v0 >> 16);
        const float w1 = bf2f(v1 >> 16);
        const float w2 = bf2f(v2 >> 16);
        const float w3 = bf2f(v3 >> 16);
        const uint4 B0 = *(const uint4*)&hb[(size_t)(v0 & 0xffffu) * DIM + q * 8];
        const uint4 B1 = *(const uint4*)&hb[(size_t)(v1 & 0xffffu) * DIM + q * 8];
        const uint4 B2 = *(const uint4*)&hb[(size_t)(v2 & 0xffffu) * DIM + q * 8];
        const uint4 B3 = *(const uint4*)&hb[(size_t)(v3 & 0xffffu) * DIM + q * 8];
        acc[0] += w0 * bf2f(B0.x & 0xffff) + w1 * bf2f(B1.x & 0xffff)
                + w2 * bf2f(B2.x & 0xffff) + w3 * bf2f(B3.x & 0xffff);
        acc[1] += w0 * bf2f(B0.x >> 16)    + w1 * bf2f(B1.x >> 16)
                + w2 * bf2f(B2.x >> 16)    + w3 * bf2f(B3.x >> 16);
        acc[2] += w0 * bf2f(B0.y & 0xffff) + w1 * bf2f(B1.y & 0xffff)
                + w2 * bf2f(B2.y & 0xffff) + w3 * bf2f(B3.y & 0xffff);
        acc[3] += w0 * bf2f(B0.y >> 16)    + w1 * bf2f(B1.y >> 16)
                + w2 * bf2f(B2.y >> 16)    + w3 * bf2f(B3.y >> 16);
        acc[4] += w0 * bf2f(B0.z & 0xffff) + w1 * bf2f(B1.z & 0xffff)
                + w2 * bf2f(B2.z & 0xffff) + w3 * bf2f(B3.z & 0xffff);
        acc[5] += w0 * bf2f(B0.z >> 16)    + w1 * bf2f(B1.z >> 16)
                + w2 * bf2f(B2.z >> 16)    + w3 * bf2f(B3.z >> 16);
        acc[6] += w0 * bf2f(B0.w & 0xffff) + w1 * bf2f(B1.w & 0xffff)
                + w2 * bf2f(B2.w & 0xffff) + w3 * bf2f(B3.w & 0xffff);
        acc[7] += w0 * bf2f(B0.w >> 16)    + w1 * bf2f(B1.w >> 16)
                + w2 * bf2f(B2.w >> 16)    + w3 * bf2f(B3.w >> 16);
    }

    // self terms: wave handles nodes m*64 + wave*8 + g (each exactly once)
    {
        const int node = m * 64 + wave * 8 + g;
        const float dv = dinv[node];
        const uint4 S = *(const uint4*)&hb[(size_t)node * DIM + q * 8];
        acc[0] += dv * bf2f(S.x & 0xffff);
        acc[1] += dv * bf2f(S.x >> 16);
        acc[2] += dv * bf2f(S.y & 0xffff);
        acc[3] += dv * bf2f(S.y >> 16);
        acc[4] += dv * bf2f(S.z & 0xffff);
        acc[5] += dv * bf2f(S.z >> 16);
        acc[6] += dv * bf2f(S.w & 0xffff);
        acc[7] += dv * bf2f(S.w >> 16);
    }

#pragma unroll
    for (int mm = 8; mm <= 32; mm <<= 1) {
#pragma unroll
        for (int k = 0; k < 8; ++k) acc[k] += __shfl_xor(acc[k], mm, 64);
    }
    if (lane < 8) {
#pragma unroll
        for (int k = 0; k < 8; ++k) wacc[wave][q * 8 + k] = acc[k];
    }
    __syncthreads();
    if (t < DIM) {
        float p = 0.f;
#pragma unroll
        for (int w = 0; w < 8; ++w) p += wacc[w][t];
        pooled[t] = p * (1.0f / DIM);
    }
    __syncthreads();
    if (t < DIM) {
        float o = b2[t];
#pragma unroll
        for (int k = 0; k < DIM; ++k) o += pooled[k] * Ws[k * DIM + t];
        out[(size_t)t * M_POOL + m] = o;
    }
}

// ---------------- launcher --------------------------------------------------

extern "C" void kernel_launch(void* const* d_in, const int* in_sizes, int n_in,
                              void* d_out, int out_size, void* d_ws, size_t ws_size,
                              hipStream_t stream) {
    const float* x  = (const float*)d_in[0];
    const int*   ei = (const int*)d_in[1];   // [2][E]
    const float* ew = (const float*)d_in[2];
    const float* W1 = (const float*)d_in[3];
    const float* b1 = (const float*)d_in[4];
    const float* W2 = (const float*)d_in[5];
    const float* b2 = (const float*)d_in[6];
    float* out = (float*)d_out;

    char* w = (char*)d_ws;
    int*   cursor = (int*)w;   w += 1024;
    int*   rowptr = (int*)w;   w += (size_t)(N_NODES + 16) * 4;      // 0.25 MB
    float* dinv   = (float*)w; w += (size_t)N_NODES * 4;             // 0.25 MB
    int2*  csrt   = (int2*)w;  w += (size_t)NCOARSE * SEGCAP * 8;    // 10.5 MB
    u32*   csr    = (u32*)w;   w += (size_t)N_EDGES * 4;             // 4 MB
    u16*   hbf    = (u16*)w;   w += (size_t)N_NODES * DIM * 2;       // 8 MB
    u16*   h1bf   = (u16*)w;                                         // 8 MB

    const int* row = ei;             // edge_index[0]
    const int* col = ei + N_EDGES;   // edge_index[1]

    // build: gemm || coarse-multisplit in one grid, then fine sort (+scan inlined)
    zero_cursor<<<1, 256, 0, stream>>>(cursor);
    fused_gemm_p3<<<FUSED_BLOCKS, 256, 0, stream>>>(x, W1, hbf, col, row, ew,
                                                    cursor, csrt);
    p4_fine<<<NCOARSE, 512, 0, stream>>>(cursor, csrt, csr, rowptr, dinv, hbf);

    // layer 1 aggregate: h1p = bf16(dv * (A h + b1))   (premultiplied)
    aggregate_l1<<<N_NODES / 4, 256, 0, stream>>>(rowptr, csr, hbf, dinv, b1, h1bf);

    // layer 2 + pool + W2-GEMM fused per window (flat contiguous edge range)
    agg2_pool_gemm<<<M_POOL, 512, 0, stream>>>(rowptr, csr, h1bf, dinv, W2, b2, out);
}

// Round 17
// 108.940 us; speedup vs baseline: 1.1349x; 1.0425x over previous
//
#include <hip/hip_runtime.h>

#define N_NODES 65536
#define N_EDGES 1048576
#define DIM 64
#define M_POOL (N_NODES / DIM)  // 1024
#define NCOARSE 256             // coarse buckets (col>>8), 256 nodes each
#define SEGCAP 5120             // fixed region per coarse bucket (mean 4096 + 16 sigma)
#define P3CHUNK 4096            // edges per p3 block (16/thread @ 256 thr)
#define P3BLOCKS (N_EDGES / P3CHUNK)   // 256
#define GEMM_ROWS 64
#define GEMM_BLOCKS (N_NODES / GEMM_ROWS)      // 1024
#define FUSED_BLOCKS (GEMM_BLOCKS + P3BLOCKS)  // 1280, 4:1 interleave
#define CURPAD 16               // cursor padding: 1 counter per 64B line

typedef unsigned int u32;
typedef unsigned short u16;

__device__ __forceinline__ float bf2f(u32 hi16) {
    return __uint_as_float(hi16 << 16);
}
__device__ __forceinline__ u32 f2bf(float f) {  // RNE
    u32 u = __float_as_uint(f);
    return (u + 0x7fffu + ((u >> 16) & 1u)) >> 16;
}

// inclusive scan of arr[256] by threads t<256 (4 full waves), 2 syncs.
__device__ __forceinline__ void scan256_wave(int* arr, int* wsum, int t) {
    int s = 0;
    if (t < 256) {
        s = arr[t];
        const int lane = t & 63;
#pragma unroll
        for (int o = 1; o < 64; o <<= 1) {
            const int u = __shfl_up(s, o, 64);
            if (lane >= o) s += u;
        }
        if (lane == 63) wsum[t >> 6] = s;
    }
    __syncthreads();
    if (t < 256) {
        const int w = t >> 6;
        int add = 0;
#pragma unroll
        for (int k = 0; k < 4; ++k)
            if (k < w) add += wsum[k];
        arr[t] = s + add;
    }
    __syncthreads();
}

// ---------------- zero the padded coarse cursors ----------------

__global__ __launch_bounds__(256) void zero_cursor(int* __restrict__ cursor) {
    for (int i = threadIdx.x; i < NCOARSE * CURPAD; i += 256) cursor[i] = 0;
}

// ---------------- fused: layer-1 GEMM (4x4 reg tile) || coarse multisplit ---
// 1280 blocks x 256 thr, 4:1. b%5==4 -> p3 chunk b/5 (4096 edges, 16/thread,
// direct global scatter, line-padded cursor); else gemm tile (b-b/5)*64 rows.

__global__ __launch_bounds__(256) void fused_gemm_p3(const float* __restrict__ x,
                                                     const float* __restrict__ W,
                                                     u16* __restrict__ hb,
                                                     const int* __restrict__ col,
                                                     const int* __restrict__ row,
                                                     const float* __restrict__ ew,
                                                     int* __restrict__ cursor,
                                                     int2* __restrict__ csr_tmp) {
    __shared__ __align__(16) char sm[33808];
    const int t = threadIdx.x;
    const int b = blockIdx.x;

    if ((b % 5) == 4) {
        // ---- p3 block: coarse multisplit of chunk b/5, direct writes ----
        int* h2       = (int*)sm;                 // 1024 B
        int* off      = (int*)(sm + 1024);        // 1024 B
        int* base_blk = (int*)(sm + 2048);        // 1024 B
        int* wsum     = (int*)(sm + 3072);        //   16 B
        const int e0 = (b / 5) * P3CHUNK + t * 16;

        h2[t] = 0;
        __syncthreads();

        int cc[16], rr[16];
        float wv[16];
#pragma unroll
        for (int jj = 0; jj < 4; ++jj) {
            const int4 c4 = *(const int4*)&col[e0 + jj * 4];
            const int4 r4 = *(const int4*)&row[e0 + jj * 4];
            const float4 w4 = *(const float4*)&ew[e0 + jj * 4];
            cc[jj * 4 + 0] = c4.x; cc[jj * 4 + 1] = c4.y;
            cc[jj * 4 + 2] = c4.z; cc[jj * 4 + 3] = c4.w;
            rr[jj * 4 + 0] = r4.x; rr[jj * 4 + 1] = r4.y;
            rr[jj * 4 + 2] = r4.z; rr[jj * 4 + 3] = r4.w;
            wv[jj * 4 + 0] = w4.x; wv[jj * 4 + 1] = w4.y;
            wv[jj * 4 + 2] = w4.z; wv[jj * 4 + 3] = w4.w;
        }
#pragma unroll
        for (int j = 0; j < 16; ++j) atomicAdd(&h2[cc[j] >> 8], 1);
        __syncthreads();

        const int myc = h2[t];
        off[t] = myc;
        __syncthreads();
        scan256_wave(off, wsum, t);               // inclusive, 2 syncs
        off[t] -= myc;                            // exclusive (own slot)
        base_blk[t] = myc ? atomicAdd(&cursor[t * CURPAD], myc) : 0;
        h2[t] = 0;
        __syncthreads();

#pragma unroll
        for (int j = 0; j < 16; ++j) {
            const int c = cc[j] >> 8;
            const int r = atomicAdd(&h2[c], 1);
            const int bp = base_blk[c] + r;
            if (bp < SEGCAP)
                csr_tmp[c * SEGCAP + bp] =
                    make_int2((rr[j] << 8) | (cc[j] & 255), __float_as_int(wv[j]));
        }
    } else {
        // ---- gemm block: 64 rows x 64 cols, 4x4 register tile per thread ----
        float* Ws  = (float*)sm;                  // 16384 B: [64][64] k-major
        float* XsT = (float*)(sm + 16384);        // 17408 B: [64 k][68] (padded)
        const int row0 = (b - b / 5) * GEMM_ROWS;
        for (int i = t; i < DIM * DIM; i += 256) Ws[i] = W[i];
        for (int i = t; i < GEMM_ROWS * DIM; i += 256) {
            const int r = i >> 6;
            const int k = i & 63;
            XsT[k * 68 + r] = x[(size_t)(row0 + r) * DIM + k];
        }
        __syncthreads();

        const int tr = t >> 4;    // 0..15 -> rows tr*4..+3
        const int tc = t & 15;    // 0..15 -> cols tc*4..+3
        float4 a0 = {0.f, 0.f, 0.f, 0.f};
        float4 a1 = a0, a2 = a0, a3 = a0;
#pragma unroll
        for (int k = 0; k < DIM; ++k) {
            const float4 xv = *(const float4*)&XsT[k * 68 + tr * 4];
            const float4 wv = *(const float4*)&Ws[k * DIM + tc * 4];
            a0.x += xv.x * wv.x; a0.y += xv.x * wv.y;
            a0.z += xv.x * wv.z; a0.w += xv.x * wv.w;
            a1.x += xv.y * wv.x; a1.y += xv.y * wv.y;
            a1.z += xv.y * wv.z; a1.w += xv.y * wv.w;
            a2.x += xv.z * wv.x; a2.y += xv.z * wv.y;
            a2.z += xv.z * wv.z; a2.w += xv.z * wv.w;
            a3.x += xv.w * wv.x; a3.y += xv.w * wv.y;
            a3.z += xv.w * wv.z; a3.w += xv.w * wv.w;
        }
        const size_t base = (size_t)(row0 + tr * 4) * DIM + tc * 4;
        ushort4 o;
        o.x = (u16)f2bf(a0.x); o.y = (u16)f2bf(a0.y);
        o.z = (u16)f2bf(a0.z); o.w = (u16)f2bf(a0.w);
        *(ushort4*)&hb[base] = o;
        o.x = (u16)f2bf(a1.x); o.y = (u16)f2bf(a1.y);
        o.z = (u16)f2bf(a1.z); o.w = (u16)f2bf(a1.w);
        *(ushort4*)&hb[base + DIM] = o;
        o.x = (u16)f2bf(a2.x); o.y = (u16)f2bf(a2.y);
        o.z = (u16)f2bf(a2.z); o.w = (u16)f2bf(a2.w);
        *(ushort4*)&hb[base + 2 * DIM] = o;
        o.x = (u16)f2bf(a3.x); o.y = (u16)f2bf(a3.y);
        o.z = (u16)f2bf(a3.z); o.w = (u16)f2bf(a3.w);
        *(ushort4*)&hb[base + 3 * DIM] = o;
    }
}

// ---------------- P4: fine sort + dinv + rowptr + premult; 4B csr out -------

__global__ __launch_bounds__(512) void p4_fine(const int* __restrict__ cursor,
                                               const int2* __restrict__ csr_tmp,
                                               u32* __restrict__ csr,
                                               int* __restrict__ rowptr,
                                               float* __restrict__ dinv,
                                               u16* __restrict__ hb) {
    __shared__ int2 A[SEGCAP];          // 40 KB
    __shared__ u32 Bu[SEGCAP];          // 20 KB
    __shared__ int fh[NCOARSE];
    __shared__ int off2[NCOARSE];
    __shared__ int cbase[NCOARSE];
    __shared__ float degw[NCOARSE];
    __shared__ float dvs[NCOARSE];
    __shared__ int wsum[4];
    const int t = threadIdx.x;
    const int c = blockIdx.x;
    const int segN = min(cursor[c * CURPAD], SEGCAP);

    // inclusive scan of clamped cursors -> output base for bucket c
    if (t < NCOARSE) cbase[t] = min(cursor[t * CURPAD], SEGCAP);
    __syncthreads();
    scan256_wave(cbase, wsum, t);
    const int seg0_out = cbase[c] - segN;

    for (int i = t; i < segN; i += 512) A[i] = csr_tmp[c * SEGCAP + i];
    if (t < NCOARSE) { fh[t] = 0; degw[t] = 0.f; }
    __syncthreads();

    for (int i = t; i < segN; i += 512) {
        const int f = A[i].x & 255;
        atomicAdd(&fh[f], 1);
        atomicAdd(&degw[f], __int_as_float(A[i].y));
    }
    __syncthreads();

    if (t < NCOARSE) off2[t] = fh[t];
    __syncthreads();
    scan256_wave(off2, wsum, t);
    if (t < NCOARSE) {
        off2[t] -= fh[t];                         // exclusive
        const float dv = rsqrtf(1.0f + degw[t]);
        dvs[t] = dv;
        dinv[c * 256 + t] = dv;
        rowptr[c * 256 + t] = seg0_out + off2[t];
        fh[t] = 0;                                // reset for rank pass
    }
    if (c == NCOARSE - 1 && t == 0) rowptr[N_NODES] = seg0_out + segN;
    __syncthreads();

    // premultiply hb rows of this bucket's 256 nodes by their dinv
    for (int idx = t; idx < 256 * 8; idx += 512) {
        const int nl = idx >> 3;
        const int part = idx & 7;
        const float dv = dvs[nl];
        const size_t p = (size_t)(c * 256 + nl) * DIM + part * 8;
        uint4 v = *(const uint4*)&hb[p];
        uint4 o;
        o.x = f2bf(dv * bf2f(v.x & 0xffff)) | (f2bf(dv * bf2f(v.x >> 16)) << 16);
        o.y = f2bf(dv * bf2f(v.y & 0xffff)) | (f2bf(dv * bf2f(v.y >> 16)) << 16);
        o.z = f2bf(dv * bf2f(v.z & 0xffff)) | (f2bf(dv * bf2f(v.z >> 16)) << 16);
        o.w = f2bf(dv * bf2f(v.w & 0xffff)) | (f2bf(dv * bf2f(v.w >> 16)) << 16);
        *(uint4*)&hb[p] = o;
    }

    for (int i = t; i < segN; i += 512) {
        const int f = A[i].x & 255;
        const int r = atomicAdd(&fh[f], 1);
        const float w = __int_as_float(A[i].y) * dvs[f];
        Bu[off2[f] + r] = (f2bf(w) << 16) | ((u32)(A[i].x >> 8) & 0xffffu);
    }
    __syncthreads();
    for (int i = t; i < segN; i += 512)           // fully coalesced
        csr[seg0_out + i] = Bu[i];
}

// ---------------- aggregate layer 1 (4B csr; premult tables) ----------------
// h1p = bf16( dv * ( sum(w_e * hb2[src_e]) + dv*hb2[node] + bias ) )

__global__ __launch_bounds__(256) void aggregate_l1(const int* __restrict__ rowptr,
                                                    const u32* __restrict__ csr,
                                                    const u16* __restrict__ hb2,
                                                    const float* __restrict__ dinv,
                                                    const float* __restrict__ bias,
                                                    u16* __restrict__ ob) {
    const int lane = threadIdx.x & 63;
    const int node = (blockIdx.x * 256 + threadIdx.x) >> 6;
    const int g = lane >> 3;
    const int q = lane & 7;
    const int start = rowptr[node];
    const int end = rowptr[node + 1];
    const float dv = dinv[node];

    float acc[8];
#pragma unroll
    for (int k = 0; k < 8; ++k) acc[k] = 0.f;

    for (int i = start; i < end; i += 16) {
        const int i0 = i + g;
        const int i1 = i + 8 + g;
        const u32 v0 = (i0 < end) ? csr[i0] : 0;
        const u32 v1 = (i1 < end) ? csr[i1] : 0;
        const float w0 = bf2f(v0 >> 16);
        const float w1 = bf2f(v1 >> 16);
        const uint4 B0 = *(const uint4*)&hb2[(size_t)(v0 & 0xffffu) * DIM + q * 8];
        const uint4 B1 = *(const uint4*)&hb2[(size_t)(v1 & 0xffffu) * DIM + q * 8];
        acc[0] += w0 * bf2f(B0.x & 0xffff) + w1 * bf2f(B1.x & 0xffff);
        acc[1] += w0 * bf2f(B0.x >> 16)    + w1 * bf2f(B1.x >> 16);
        acc[2] += w0 * bf2f(B0.y & 0xffff) + w1 * bf2f(B1.y & 0xffff);
        acc[3] += w0 * bf2f(B0.y >> 16)    + w1 * bf2f(B1.y >> 16);
        acc[4] += w0 * bf2f(B0.z & 0xffff) + w1 * bf2f(B1.z & 0xffff);
        acc[5] += w0 * bf2f(B0.z >> 16)    + w1 * bf2f(B1.z >> 16);
        acc[6] += w0 * bf2f(B0.w & 0xffff) + w1 * bf2f(B1.w & 0xffff);
        acc[7] += w0 * bf2f(B0.w >> 16)    + w1 * bf2f(B1.w >> 16);
    }
#pragma unroll
    for (int m = 8; m <= 32; m <<= 1) {
#pragma unroll
        for (int k = 0; k < 8; ++k) acc[k] += __shfl_xor(acc[k], m, 64);
    }
    if (lane < 8) {
        const uint4 S = *(const uint4*)&hb2[(size_t)node * DIM + q * 8];
        float r[8];
        r[0] = dv * (acc[0] + dv * bf2f(S.x & 0xffff) + bias[q * 8 + 0]);
        r[1] = dv * (acc[1] + dv * bf2f(S.x >> 16)    + bias[q * 8 + 1]);
        r[2] = dv * (acc[2] + dv * bf2f(S.y & 0xffff) + bias[q * 8 + 2]);
        r[3] = dv * (acc[3] + dv * bf2f(S.y >> 16)    + bias[q * 8 + 3]);
        r[4] = dv * (acc[4] + dv * bf2f(S.z & 0xffff) + bias[q * 8 + 4]);
        r[5] = dv * (acc[5] + dv * bf2f(S.z >> 16)    + bias[q * 8 + 5]);
        r[6] = dv * (acc[6] + dv * bf2f(S.w & 0xffff) + bias[q * 8 + 6]);
        r[7] = dv * (acc[7] + dv * bf2f(S.w >> 16)    + bias[q * 8 + 7]);
        uint4 o;
        o.x = f2bf(r[0]) | (f2bf(r[1]) << 16);
        o.y = f2bf(r[2]) | (f2bf(r[3]) << 16);
        o.z = f2bf(r[4]) | (f2bf(r[5]) << 16);
        o.w = f2bf(r[6]) | (f2bf(r[7]) << 16);
        *(uint4*)&ob[(size_t)node * DIM + q * 8] = o;
    }
}

// ---------------- fused: layer-2 aggregate + pool + W2 GEMM (flat range) ----

__global__ __launch_bounds__(512) void agg2_pool_gemm(const int* __restrict__ rowptr,
                                                      const u32* __restrict__ csr,
                                                      const u16* __restrict__ hb,
                                                      const float* __restrict__ dinv,
                                                      const float* __restrict__ W2,
                                                      const float* __restrict__ b2,
                                                      float* __restrict__ out) {
    __shared__ float Ws[DIM * DIM];
    __shared__ float wacc[8][DIM];
    __shared__ float pooled[DIM];
    const int t = threadIdx.x;
    const int m = blockIdx.x;

    for (int i = t; i < DIM * DIM; i += 512) Ws[i] = W2[i];

    const int wave = t >> 6;
    const int lane = t & 63;
    const int g = lane >> 3;
    const int q = lane & 7;

    const int start = rowptr[m * 64];
    const int end = rowptr[m * 64 + 64];

    float acc[8];
#pragma unroll
    for (int k = 0; k < 8; ++k) acc[k] = 0.f;

    for (int i = start + wave * 32; i < end; i += 256) {
        const int i0 = i + g;
        const int i1 = i + 8 + g;
        const int i2 = i + 16 + g;
        const int i3 = i + 24 + g;
        const u32 v0 = (i0 < end) ? csr[i0] : 0;
        const u32 v1 = (i1 < end) ? csr[i1] : 0;
        const u32 v2 = (i2 < end) ? csr[i2] : 0;
        const u32 v3 = (i3 < end) ? csr[i3] : 0;
        const float w0 = bf2f(v0 >> 16);
        const float w1 = bf2f(v1 >> 16);
        const float w2 = bf2f(v2 >> 16);
        const float w3 = bf2f(v3 >> 16);
        const uint4 B0 = *(const uint4*)&hb[(size_t)(v0 & 0xffffu) * DIM + q * 8];
        const uint4 B1 = *(const uint4*)&hb[(size_t)(v1 & 0xffffu) * DIM + q * 8];
        const uint4 B2 = *(const uint4*)&hb[(size_t)(v2 & 0xffffu) * DIM + q * 8];
        const uint4 B3 = *(const uint4*)&hb[(size_t)(v3 & 0xffffu) * DIM + q * 8];
        acc[0] += w0 * bf2f(B0.x & 0xffff) + w1 * bf2f(B1.x & 0xffff)
                + w2 * bf2f(B2.x & 0xffff) + w3 * bf2f(B3.x & 0xffff);
        acc[1] += w0 * bf2f(B0.x >> 16)    + w1 * bf2f(B1.x >> 16)
                + w2 * bf2f(B2.x >> 16)    + w3 * bf2f(B3.x >> 16);
        acc[2] += w0 * bf2f(B0.y & 0xffff) + w1 * bf2f(B1.y & 0xffff)
                + w2 * bf2f(B2.y & 0xffff) + w3 * bf2f(B3.y & 0xffff);
        acc[3] += w0 * bf2f(B0.y >> 16)    + w1 * bf2f(B1.y >> 16)
                + w2 * bf2f(B2.y >> 16)    + w3 * bf2f(B3.y >> 16);
        acc[4] += w0 * bf2f(B0.z & 0xffff) + w1 * bf2f(B1.z & 0xffff)
                + w2 * bf2f(B2.z & 0xffff) + w3 * bf2f(B3.z & 0xffff);
        acc[5] += w0 * bf2f(B0.z >> 16)    + w1 * bf2f(B1.z >> 16)
                + w2 * bf2f(B2.z >> 16)    + w3 * bf2f(B3.z >> 16);
        acc[6] += w0 * bf2f(B0.w & 0xffff) + w1 * bf2f(B1.w & 0xffff)
                + w2 * bf2f(B2.w & 0xffff) + w3 * bf2f(B3.w & 0xffff);
        acc[7] += w0 * bf2f(B0.w >> 16)    + w1 * bf2f(B1.w >> 16)
                + w2 * bf2f(B2.w >> 16)    + w3 * bf2f(B3.w >> 16);
    }

    // self terms: wave handles nodes m*64 + wave*8 + g (each exactly once)
    {
        const int node = m * 64 + wave * 8 + g;
        const float dv = dinv[node];
        const uint4 S = *(const uint4*)&hb[(size_t)node * DIM + q * 8];
        acc[0] += dv * bf2f(S.x & 0xffff);
        acc[1] += dv * bf2f(S.x >> 16);
        acc[2] += dv * bf2f(S.y & 0xffff);
        acc[3] += dv * bf2f(S.y >> 16);
        acc[4] += dv * bf2f(S.z & 0xffff);
        acc[5] += dv * bf2f(S.z >> 16);
        acc[6] += dv * bf2f(S.w & 0xffff);
        acc[7] += dv * bf2f(S.w >> 16);
    }

#pragma unroll
    for (int mm = 8; mm <= 32; mm <<= 1) {
#pragma unroll
        for (int k = 0; k < 8; ++k) acc[k] += __shfl_xor(acc[k], mm, 64);
    }
    if (lane < 8) {
#pragma unroll
        for (int k = 0; k < 8; ++k) wacc[wave][q * 8 + k] = acc[k];
    }
    __syncthreads();
    if (t < DIM) {
        float p = 0.f;
#pragma unroll
        for (int w = 0; w < 8; ++w) p += wacc[w][t];
        pooled[t] = p * (1.0f / DIM);
    }
    __syncthreads();
    if (t < DIM) {
        float o = b2[t];
#pragma unroll
        for (int k = 0; k < DIM; ++k) o += pooled[k] * Ws[k * DIM + t];
        out[(size_t)t * M_POOL + m] = o;
    }
}

// ---------------- launcher --------------------------------------------------

extern "C" void kernel_launch(void* const* d_in, const int* in_sizes, int n_in,
                              void* d_out, int out_size, void* d_ws, size_t ws_size,
                              hipStream_t stream) {
    const float* x  = (const float*)d_in[0];
    const int*   ei = (const int*)d_in[1];   // [2][E]
    const float* ew = (const float*)d_in[2];
    const float* W1 = (const float*)d_in[3];
    const float* b1 = (const float*)d_in[4];
    const float* W2 = (const float*)d_in[5];
    const float* b2 = (const float*)d_in[6];
    float* out = (float*)d_out;

    char* w = (char*)d_ws;
    int*   cursor = (int*)w;   w += (size_t)NCOARSE * CURPAD * 4;    // 16 KB padded
    int*   rowptr = (int*)w;   w += (size_t)(N_NODES + 16) * 4;      // 0.25 MB
    float* dinv   = (float*)w; w += (size_t)N_NODES * 4;             // 0.25 MB
    int2*  csrt   = (int2*)w;  w += (size_t)NCOARSE * SEGCAP * 8;    // 10.5 MB
    u32*   csr    = (u32*)w;   w += (size_t)N_EDGES * 4;             // 4 MB
    u16*   hbf    = (u16*)w;   w += (size_t)N_NODES * DIM * 2;       // 8 MB
    u16*   h1bf   = (u16*)w;                                         // 8 MB

    const int* row = ei;             // edge_index[0]
    const int* col = ei + N_EDGES;   // edge_index[1]

    // build: gemm || coarse-multisplit in one grid, then fine sort (+scan inlined)
    zero_cursor<<<1, 256, 0, stream>>>(cursor);
    fused_gemm_p3<<<FUSED_BLOCKS, 256, 0, stream>>>(x, W1, hbf, col, row, ew,
                                                    cursor, csrt);
    p4_fine<<<NCOARSE, 512, 0, stream>>>(cursor, csrt, csr, rowptr, dinv, hbf);

    // layer 1 aggregate: h1p = bf16(dv * (A h + b1))   (premultiplied)
    aggregate_l1<<<N_NODES / 4, 256, 0, stream>>>(rowptr, csr, hbf, dinv, b1, h1bf);

    // layer 2 + pool + W2-GEMM fused per window (flat contiguous edge range)
    agg2_pool_gemm<<<M_POOL, 512, 0, stream>>>(rowptr, csr, h1bf, dinv, W2, b2, out);
}